// Round 4
// baseline (5463.165 us; speedup 1.0000x reference)
//
#include <hip/hip_runtime.h>
#include <math.h>

// G=128, S=32, P=16, D=768, C=256, NH=4, OUT=7; NR = G*P = 2048
#define NG 128
#define NS 32
#define NP 16
#define ND 768
#define NC 256
#define NHD 4
#define NOUT 7

typedef unsigned short ushortT;
typedef short bf16x8 __attribute__((ext_vector_type(8)));
typedef float f32x4 __attribute__((ext_vector_type(4)));

__device__ __forceinline__ ushortT f2b(float f) {
    union { float f; unsigned u; } v; v.f = f;
    unsigned r = (v.u + 0x7FFF + ((v.u >> 16) & 1)) >> 16;
    return (ushortT)r;
}
__device__ __forceinline__ float b2f(ushortT u) {
    union { unsigned u; float f; } v; v.u = ((unsigned)u) << 16; return v.f;
}
__device__ __forceinline__ float sigf(float v) { return 1.f / (1.f + expf(-v)); }

#define MFMA16(a, b, c) __builtin_amdgcn_mfma_f32_16x16x32_bf16((a), (b), (c), 0, 0, 0)
#define ZERO4 ((f32x4){0.f, 0.f, 0.f, 0.f})

// ---------------------------------------------------------------------------
// Generic bf16 MFMA GEMM, 64x64 tile (weight prep only).
// A [M,K] bf16 row-major; Bt [N,K] bf16; outH bf16 [M,N].
// ---------------------------------------------------------------------------
__global__ __launch_bounds__(256) void bgemm_kernel(
    const ushortT* __restrict__ A, const ushortT* __restrict__ Bt,
    ushortT* __restrict__ outH, int N, int K)
{
    __shared__ short As[64 * 40];
    __shared__ short Bs[64 * 40];
    const int tid = threadIdx.x;
    const int lane = tid & 63, wid = tid >> 6;
    const int quad = lane >> 4, l15 = lane & 15;
    const int row0 = blockIdx.y * 64, col0 = blockIdx.x * 64;
    const int mh = (wid & 1) * 32, nh = (wid >> 1) * 32;
    const int sr = tid >> 2, skq = (tid & 3) * 8;
    const ushortT* aptr = A + (size_t)(row0 + sr) * K;
    const ushortT* bptr = Bt + (size_t)(col0 + sr) * K;

    f32x4 acc[2][2] = {{ZERO4, ZERO4}, {ZERO4, ZERO4}};
    for (int kk = 0; kk < K; kk += 32) {
        __syncthreads();
        *(uint4*)&As[sr * 40 + skq] = *(const uint4*)(aptr + kk + skq);
        *(uint4*)&Bs[sr * 40 + skq] = *(const uint4*)(bptr + kk + skq);
        __syncthreads();
        bf16x8 af0 = *(const bf16x8*)&As[(mh + l15) * 40 + quad * 8];
        bf16x8 af1 = *(const bf16x8*)&As[(mh + 16 + l15) * 40 + quad * 8];
        bf16x8 bf0 = *(const bf16x8*)&Bs[(nh + l15) * 40 + quad * 8];
        bf16x8 bf1 = *(const bf16x8*)&Bs[(nh + 16 + l15) * 40 + quad * 8];
        acc[0][0] = MFMA16(af0, bf0, acc[0][0]);
        acc[0][1] = MFMA16(af0, bf1, acc[0][1]);
        acc[1][0] = MFMA16(af1, bf0, acc[1][0]);
        acc[1][1] = MFMA16(af1, bf1, acc[1][1]);
    }
#pragma unroll
    for (int mt = 0; mt < 2; ++mt)
#pragma unroll
        for (int nt = 0; nt < 2; ++nt) {
            const int gc = col0 + nh + nt * 16 + l15;
#pragma unroll
            for (int r = 0; r < 4; ++r) {
                const int gr = row0 + mh + mt * 16 + quad * 4 + r;
                outH[(size_t)gr * N + gc] = f2b(acc[mt][nt][r]);
            }
        }
}

// ---------------------------------------------------------------------------
// Prep kernels
// ---------------------------------------------------------------------------
__global__ __launch_bounds__(256) void cast_kernel(const float* __restrict__ a,
                                                   ushortT* __restrict__ b, int n) {
    const int i = blockIdx.x * 256 + threadIdx.x;
    if (i < n) b[i] = f2b(a[i]);
}
// gatB[c][d] = gat_W[d][c]  (BT layout, bf16)
__global__ __launch_bounds__(256) void gatT_kernel(const float* __restrict__ gW,
                                                   ushortT* __restrict__ gB) {
    const int idx = blockIdx.x * 256 + threadIdx.x; // < 1024*768
    const int c = idx / ND, d = idx - c * ND;
    gB[idx] = f2b(gW[(size_t)d * (NHD * NC) + c]);
}
// spwcB[o][d] = sp_W[o][d] + sp_W[o][d+768]  (bf16)
__global__ __launch_bounds__(256) void spwcB_kernel(const float* __restrict__ spW,
                                                    ushortT* __restrict__ o) {
    const int idx = blockIdx.x * 256 + threadIdx.x; // < 768*768
    const int r = idx / ND, d = idx - r * ND;
    o[idx] = f2b(spW[(size_t)r * (2 * ND) + d] + spW[(size_t)r * (2 * ND) + ND + d]);
}
// upWTc[c][d] = up_W[d][c]  (bf16)
__global__ __launch_bounds__(256) void upTc_kernel(const float* __restrict__ upW,
                                                   ushortT* __restrict__ o) {
    const int idx = blockIdx.x * 256 + threadIdx.x; // < 256*768
    if (idx >= NC * ND) return;
    const int c = idx / ND, d = idx - c * ND;
    o[idx] = f2b(upW[(size_t)d * NC + c]);
}
// bus[o] = sp_b[o] + sum_d (spW[o][d]+spW[o][d+768]) * up_b[d]
__global__ __launch_bounds__(256) void bus_kernel(const float* __restrict__ spW,
                                                  const float* __restrict__ up_b,
                                                  const float* __restrict__ sp_b,
                                                  float* __restrict__ bus) {
    const int o = blockIdx.x * 256 + threadIdx.x;
    if (o >= ND) return;
    float a = sp_b[o];
    const float* sr = spW + (size_t)o * (2 * ND);
    for (int d = 0; d < ND; ++d) a += (sr[d] + sr[ND + d]) * up_b[d];
    bus[o] = a;
}
// bug[col] = sum_d gatB[col][d] * up_b[d]
__global__ __launch_bounds__(256) void bug_kernel(const ushortT* __restrict__ gatB,
                                                  const float* __restrict__ up_b,
                                                  float* __restrict__ bug) {
    const int col = blockIdx.x * 256 + threadIdx.x; // < 1024
    float a = 0.f;
    const ushortT* gr = gatB + (size_t)col * ND;
    for (int d = 0; d < ND; ++d) a += b2f(gr[d]) * up_b[d];
    bug[col] = a;
}

// ---------------------------------------------------------------------------
// Persistent per-graph scan kernel. One block per graph (128 blocks x 1024
// threads). All per-graph state lives in LDS for the full 32-step scan;
// weights streamed from L2. Zero inter-block dependencies.
// ---------------------------------------------------------------------------
__global__ __launch_bounds__(1024) void iter_kernel(
    const float* __restrict__ x,
    const ushortT* __restrict__ gatB,   // [1024][768]
    const ushortT* __restrict__ WihB,   // [768][256]
    const ushortT* __restrict__ WhhB,   // [768][256]
    const ushortT* __restrict__ WusB,   // [768][256]
    const ushortT* __restrict__ WugT,   // [1024][256]
    const float* __restrict__ bus,      // [768]
    const float* __restrict__ bug,      // [1024]
    const float* __restrict__ bih, const float* __restrict__ bhh,
    const float* __restrict__ att_src, const float* __restrict__ att_dst,
    const float* __restrict__ gat_b,
    const float* __restrict__ attW, const float* __restrict__ attb,
    const float* __restrict__ clsW, const float* __restrict__ clsb,
    float* __restrict__ outp)
{
    __shared__ short mB_s[16 * 264];    // m (bf16, GRU input)
    __shared__ short hB_s[16 * 264];    // h_run (bf16, MFMA operand)
    __shared__ short hn_s[16 * 264];    // h_nxt (bf16)
    __shared__ float hF_s[16 * 264];    // h_run (f32 state)
    __shared__ float msf[16 * 264];     // m (f32, for pool precision)
    __shared__ short hb_s[16 * 1040];   // GAT pre-activations (bf16)
    __shared__ short spk_s[776];        // relu speaker projection (bf16)
    __shared__ float es_s[64], ed_s[64];
    __shared__ float gate_s[16];
    __shared__ float pooled_s[256];

    const int g = blockIdx.x;
    const int tid = threadIdx.x;
    const int lane = tid & 63, wid = tid >> 6;
    const int quad = lane >> 4, l15 = lane & 15;

    // init state
    for (int i = tid; i < 16 * 264; i += 1024) { hF_s[i] = 0.f; hB_s[i] = 0; }
    __syncthreads();

    // column tiles owned by this wave for the N=1024 GEMMs (4 tiles of 16)
    int ct[4];
#pragma unroll
    for (int t = 0; t < 4; ++t) ct[t] = ((wid * 4 + t) << 4) + l15;

    // ---- step 0: hb = x0 @ gatW (A from global fp32, cast inline) ----
    {
        const float* xrow = x + ((size_t)g * NS * NP + l15) * ND; // s=0, p=l15
        f32x4 acc[4] = {ZERO4, ZERO4, ZERO4, ZERO4};
        for (int kk = 0; kk < ND; kk += 32) {
            const float4 xa = *(const float4*)(xrow + kk + quad * 8);
            const float4 xb2 = *(const float4*)(xrow + kk + quad * 8 + 4);
            bf16x8 a;
            a[0] = (short)f2b(xa.x); a[1] = (short)f2b(xa.y);
            a[2] = (short)f2b(xa.z); a[3] = (short)f2b(xa.w);
            a[4] = (short)f2b(xb2.x); a[5] = (short)f2b(xb2.y);
            a[6] = (short)f2b(xb2.z); a[7] = (short)f2b(xb2.w);
#pragma unroll
            for (int t = 0; t < 4; ++t) {
                bf16x8 b = *(const bf16x8*)(gatB + (size_t)ct[t] * ND + kk + quad * 8);
                acc[t] = MFMA16(a, b, acc[t]);
            }
        }
#pragma unroll
        for (int t = 0; t < 4; ++t)
#pragma unroll
            for (int r = 0; r < 4; ++r)
                hb_s[(quad * 4 + r) * 1040 + ct[t]] = (short)f2b(acc[t][r]);
    }
    __syncthreads();

    const int c_own = (wid << 4) + l15;  // hidden column owned in GRU phases

    for (int s = 0; s < NS; ++s) {
        // ================= FIN: GAT softmax/combine + pool + classify ======
        {
            const int p = wid;  // wave per node row
            float ss[4] = {0.f, 0.f, 0.f, 0.f}, sd[4] = {0.f, 0.f, 0.f, 0.f};
#pragma unroll
            for (int i = 0; i < 16; ++i) {
                const int col = lane + (i << 6);
                const float v = b2f((ushortT)hb_s[p * 1040 + col]);
                ss[i >> 2] += v * att_src[col];
                sd[i >> 2] += v * att_dst[col];
            }
            for (int off = 32; off; off >>= 1)
#pragma unroll
                for (int h = 0; h < 4; ++h) {
                    ss[h] += __shfl_down(ss[h], off);
                    sd[h] += __shfl_down(sd[h], off);
                }
            if (lane == 0)
#pragma unroll
                for (int h = 0; h < 4; ++h) { es_s[p * 4 + h] = ss[h]; ed_s[p * 4 + h] = sd[h]; }
        }
        __syncthreads();
        {
            // combine: thread -> (p = tid>>6, 4 cols at lane*4)
            const int p = tid >> 6, c0 = lane << 2;
            float accv[4] = {0.f, 0.f, 0.f, 0.f};
#pragma unroll
            for (int h = 0; h < 4; ++h) {
                float e1 = es_s[h] + ed_s[p * 4 + h];          // speaker -> p
                e1 = e1 > 0.f ? e1 : 0.2f * e1;
                float e2 = es_s[p * 4 + h] + ed_s[p * 4 + h];  // self loop
                e2 = e2 > 0.f ? e2 : 0.2f * e2;
                const float mx = fmaxf(e1, e2);
                float w0 = expf(e1 - mx), w1 = expf(e2 - mx);
                const float inv = 1.f / (w0 + w1);
                w0 *= inv; w1 *= inv;
#pragma unroll
                for (int j = 0; j < 4; ++j) {
                    const int col = h * NC + c0 + j;
                    accv[j] += w0 * b2f((ushortT)hb_s[col])
                             + w1 * b2f((ushortT)hb_s[p * 1040 + col]);
                }
            }
#pragma unroll
            for (int j = 0; j < 4; ++j) {
                const float v = accv[j] * 0.25f + gat_b[c0 + j];
                msf[p * 264 + c0 + j] = v;
                mB_s[p * 264 + c0 + j] = (short)f2b(v);
            }
        }
        __syncthreads();
        {
            const int p = wid;
            float sg = 0.f;
#pragma unroll
            for (int i = 0; i < 4; ++i) {
                const int c = lane + (i << 6);
                sg += msf[p * 264 + c] * attW[c];
            }
            for (int off = 32; off; off >>= 1) sg += __shfl_down(sg, off);
            if (lane == 0) gate_s[p] = sg + attb[0];
        }
        __syncthreads();
        if (tid < NC) {
            float mx = gate_s[0];
#pragma unroll
            for (int p = 1; p < 16; ++p) mx = fmaxf(mx, gate_s[p]);
            float sum = 0.f, pc = 0.f;
#pragma unroll
            for (int p = 0; p < 16; ++p) {
                const float e = expf(gate_s[p] - mx);
                sum += e;
                pc += e * msf[p * 264 + tid];
            }
            pooled_s[tid] = pc / sum;
        }
        __syncthreads();
        if (wid < NOUT) {
            float a = 0.f;
#pragma unroll
            for (int i = 0; i < 4; ++i) {
                const int c = lane + (i << 6);
                a += pooled_s[c] * clsW[wid * NC + c];
            }
            for (int off = 32; off; off >>= 1) a += __shfl_down(a, off);
            if (lane == 0) outp[((size_t)g * NS + s) * NOUT + wid] = a + clsb[wid];
        }
        if (s == NS - 1) break;

        // ================= GRU1: h_run update ==============================
        {
            const ushortT* bi = WihB + (size_t)c_own * NC + quad * 8;
            const ushortT* bh = WhhB + (size_t)c_own * NC + quad * 8;
            f32x4 agi[3] = {ZERO4, ZERO4, ZERO4};
            f32x4 agh[3] = {ZERO4, ZERO4, ZERO4};
            for (int kk = 0; kk < NC; kk += 32) {
                bf16x8 am = *(const bf16x8*)&mB_s[l15 * 264 + kk + quad * 8];
                bf16x8 ah = *(const bf16x8*)&hB_s[l15 * 264 + kk + quad * 8];
#pragma unroll
                for (int gt = 0; gt < 3; ++gt) {
                    bf16x8 wi = *(const bf16x8*)(bi + gt * 65536 + kk);
                    bf16x8 wh = *(const bf16x8*)(bh + gt * 65536 + kk);
                    agi[gt] = MFMA16(am, wi, agi[gt]);
                    agh[gt] = MFMA16(ah, wh, agh[gt]);
                }
            }
            __syncthreads();  // all reads of hB_s done before writes
            const float br = bih[c_own], bz = bih[NC + c_own], bn = bih[2 * NC + c_own];
            const float cr = bhh[c_own], cz = bhh[NC + c_own], cn = bhh[2 * NC + c_own];
#pragma unroll
            for (int r = 0; r < 4; ++r) {
                const int idx = (quad * 4 + r) * 264 + c_own;
                const float hold = hF_s[idx];
                const float rg = sigf(agi[0][r] + br + agh[0][r] + cr);
                const float zg = sigf(agi[1][r] + bz + agh[1][r] + cz);
                const float ng = tanhf(agi[2][r] + bn + rg * (agh[2][r] + cn));
                const float hn = (1.f - zg) * ng + zg * hold;
                hF_s[idx] = hn;
                hB_s[idx] = (short)f2b(hn);
            }
        }
        __syncthreads();

        // ================= GRU2: zero-input step -> h_nxt ==================
        {
            const ushortT* bh = WhhB + (size_t)c_own * NC + quad * 8;
            f32x4 agh[3] = {ZERO4, ZERO4, ZERO4};
            for (int kk = 0; kk < NC; kk += 32) {
                bf16x8 ah = *(const bf16x8*)&hB_s[l15 * 264 + kk + quad * 8];
#pragma unroll
                for (int gt = 0; gt < 3; ++gt) {
                    bf16x8 wh = *(const bf16x8*)(bh + gt * 65536 + kk);
                    agh[gt] = MFMA16(ah, wh, agh[gt]);
                }
            }
            const float br = bih[c_own], bz = bih[NC + c_own], bn = bih[2 * NC + c_own];
            const float cr = bhh[c_own], cz = bhh[NC + c_own], cn = bhh[2 * NC + c_own];
#pragma unroll
            for (int r = 0; r < 4; ++r) {
                const int idx = (quad * 4 + r) * 264 + c_own;
                const float rg = sigf(br + agh[0][r] + cr);
                const float zg = sigf(bz + agh[1][r] + cz);
                const float ng = tanhf(bn + rg * (agh[2][r] + cn));
                const float hv = (1.f - zg) * ng + zg * hF_s[idx];
                hn_s[idx] = (short)f2b(hv);
            }
        }
        __syncthreads();

        // ================= SPK: spk = relu(h0_nxt @ Wus^T + bus) ===========
        if (tid < ND) {
            float acc = bus[tid];
            const ushortT* wrow = WusB + (size_t)tid * NC;
            for (int k = 0; k < NC; k += 8) {
                bf16x8 hv = *(const bf16x8*)&hn_s[k];        // speaker row
                bf16x8 wv = *(const bf16x8*)(wrow + k);
#pragma unroll
                for (int j = 0; j < 8; ++j)
                    acc += b2f((ushortT)hv[j]) * b2f((ushortT)wv[j]);
            }
            spk_s[tid] = (short)f2b(fmaxf(acc, 0.f));
        }
        __syncthreads();

        // ========= P4a: hb(rows 1..15) = hn @ W_ug + b_ug ==================
        {
            f32x4 acc[4] = {ZERO4, ZERO4, ZERO4, ZERO4};
            for (int kk = 0; kk < NC; kk += 32) {
                bf16x8 a = *(const bf16x8*)&hn_s[l15 * 264 + kk + quad * 8];
#pragma unroll
                for (int t = 0; t < 4; ++t) {
                    bf16x8 b = *(const bf16x8*)(WugT + (size_t)ct[t] * NC + kk + quad * 8);
                    acc[t] = MFMA16(a, b, acc[t]);
                }
            }
#pragma unroll
            for (int t = 0; t < 4; ++t) {
                const float bv = bug[ct[t]];
#pragma unroll
                for (int r = 0; r < 4; ++r) {
                    const int row = quad * 4 + r;
                    if (row != 0)
                        hb_s[row * 1040 + ct[t]] = (short)f2b(acc[t][r] + bv);
                }
            }
        }
        // ========= P4b: hb(row 0) = spk @ gatW (MFMA, row-0 only) ==========
        {
            f32x4 acc[4] = {ZERO4, ZERO4, ZERO4, ZERO4};
            for (int kk = 0; kk < ND; kk += 32) {
                bf16x8 a;
                if (l15 == 0) a = *(const bf16x8*)&spk_s[kk + quad * 8];
                else a = (bf16x8){0, 0, 0, 0, 0, 0, 0, 0};
#pragma unroll
                for (int t = 0; t < 4; ++t) {
                    bf16x8 b = *(const bf16x8*)(gatB + (size_t)ct[t] * ND + kk + quad * 8);
                    acc[t] = MFMA16(a, b, acc[t]);
                }
            }
            if (quad == 0) {
#pragma unroll
                for (int t = 0; t < 4; ++t)
                    hb_s[ct[t]] = (short)f2b(acc[t][0]);
            }
        }
        __syncthreads();
    }
}

// ---------------------------------------------------------------------------
extern "C" void kernel_launch(void* const* d_in, const int* in_sizes, int n_in,
                              void* d_out, int out_size, void* d_ws, size_t ws_size,
                              hipStream_t stream) {
    (void)in_sizes; (void)n_in; (void)out_size; (void)ws_size;
    const float* x       = (const float*)d_in[0];
    const float* gat_W   = (const float*)d_in[1];
    const float* att_src = (const float*)d_in[2];
    const float* att_dst = (const float*)d_in[3];
    const float* gat_b   = (const float*)d_in[4];
    const float* gru_Wih = (const float*)d_in[5];
    const float* gru_Whh = (const float*)d_in[6];
    const float* gru_bih = (const float*)d_in[7];
    const float* gru_bhh = (const float*)d_in[8];
    const float* up_W    = (const float*)d_in[9];
    const float* up_b    = (const float*)d_in[10];
    const float* sp_W    = (const float*)d_in[11];
    const float* sp_b    = (const float*)d_in[12];
    const float* att_W   = (const float*)d_in[13];
    const float* att_b   = (const float*)d_in[14];
    const float* cls_W   = (const float*)d_in[15];
    const float* cls_b   = (const float*)d_in[16];
    float* outp = (float*)d_out;

    char* w = (char*)d_ws;
    ushortT* WihB  = (ushortT*)w; w += (size_t)(3 * NC) * NC * 2;
    ushortT* WhhB  = (ushortT*)w; w += (size_t)(3 * NC) * NC * 2;
    ushortT* gatB  = (ushortT*)w; w += (size_t)(NHD * NC) * ND * 2;
    ushortT* spwcB = (ushortT*)w; w += (size_t)ND * ND * 2;
    ushortT* upWTc = (ushortT*)w; w += (size_t)NC * ND * 2;
    ushortT* WusB  = (ushortT*)w; w += (size_t)ND * NC * 2;
    ushortT* WugT  = (ushortT*)w; w += (size_t)(NHD * NC) * NC * 2;
    float*   bus   = (float*)w;   w += (size_t)ND * 4;
    float*   bug   = (float*)w;   w += (size_t)(NHD * NC) * 4;

    // ---- weight prep (every call; ws is re-poisoned between calls) ----
    cast_kernel<<<768, 256, 0, stream>>>(gru_Wih, WihB, 3 * NC * NC);
    cast_kernel<<<768, 256, 0, stream>>>(gru_Whh, WhhB, 3 * NC * NC);
    gatT_kernel<<<(NHD * NC * ND) / 256, 256, 0, stream>>>(gat_W, gatB);
    spwcB_kernel<<<(ND * ND) / 256, 256, 0, stream>>>(sp_W, spwcB);
    upTc_kernel<<<(NC * ND) / 256, 256, 0, stream>>>(up_W, upWTc);
    // WusB [768][256] = spwcB [768x768] @ upWTc^T
    bgemm_kernel<<<dim3(NC / 64, ND / 64), 256, 0, stream>>>(
        spwcB, upWTc, WusB, NC, ND);
    // WugT [1024][256] = gatB [1024x768] @ upWTc^T
    bgemm_kernel<<<dim3(NC / 64, (NHD * NC) / 64), 256, 0, stream>>>(
        gatB, upWTc, WugT, NC, ND);
    bus_kernel<<<3, 256, 0, stream>>>(sp_W, up_b, sp_b, bus);
    bug_kernel<<<4, 256, 0, stream>>>(gatB, up_b, bug);

    // ---- the whole 32-step scan: one launch, one block per graph ----
    iter_kernel<<<NG, 1024, 0, stream>>>(
        x, gatB, WihB, WhhB, WusB, WugT, bus, bug,
        gru_bih, gru_bhh, att_src, att_dst, gat_b,
        att_W, att_b, cls_W, cls_b, outp);
}